// Round 18
// baseline (686.283 us; speedup 1.0000x reference)
//
#include <hip/hip_runtime.h>
#include <stdint.h>

#define HWDIM 224
#define NPIX (HWDIM*HWDIM)
#define NFIELD 12
#define TT 25

#define R1v 37
#define PW1v (HWDIM + 2*R1v)        /* 298 */
#define R2v 74
#define PW2v (HWDIM + 2*R2v)        /* 372 */

#define HSIZE 16384
#define FCAP 4096
#define RHASH 4096
#define BPF128 392                  /* 128-px blocks per field */
#define DON128 72                   /* g0 128-px blocks donated to each g1 XCD */

typedef unsigned long long u64;

struct LayerParams {
    const float* tseq[6];
    const float* gw[6];
    const float* gb[6];
};

// ---------------- workspace layout ----------------
constexpr size_t alup(size_t x) { return (x + 255) & ~(size_t)255; }
constexpr size_t SZPA = (size_t)6*PW1v*(PW1v+1)*4;
constexpr size_t SZPB = (size_t)6*PW2v*(PW2v+1)*4;
constexpr size_t OFF_SUMS = 0;
constexpr size_t OFF_P0A = alup(OFF_SUMS + 8*4);
constexpr size_t OFF_PZA = alup(OFF_P0A + SZPA);      // float2 (P1,P2)
constexpr size_t OFF_P0B = alup(OFF_PZA + 2*SZPA);
constexpr size_t OFF_PZB = alup(OFF_P0B + SZPB);
constexpr size_t OFF_DT   = alup(OFF_PZB + 2*SZPB);
constexpr size_t OFF_PAR  = alup(OFF_DT   + (size_t)NFIELD*NPIX*4);
constexpr size_t OFF_HP   = alup(OFF_PAR  + (size_t)NFIELD*NPIX*2);
constexpr size_t OFF_HB   = alup(OFF_HP   + (size_t)NFIELD*HSIZE*8);   // contiguous with HP
constexpr size_t OFF_GMM  = OFF_HB + (size_t)NFIELD*HSIZE*8;           // contiguous (0xFF memset)
constexpr size_t OFF_X    = alup(OFF_GMM + 256);

// ---------------- kernels ----------------

// f32 accumulation (reference itself uses f32 cumsum; error negligible vs 0.24).
__global__ __launch_bounds__(64) void k_prefix(const float* __restrict__ inp,
        float* __restrict__ p0a, float2* __restrict__ pza,
        float* __restrict__ p0b, float2* __restrict__ pzb) {
    int bidx = blockIdx.x;
    const int tot0 = 6 * PW1v;
    int g = (bidx >= tot0);
    int rem = g ? (bidx - tot0) : bidx;
    const int PW = g ? PW2v : PW1v, R = g ? R2v : R1v, C = PW + 1;
    int img = rem / PW, row = rem % PW;
    float* P0 = (g ? p0b : p0a) + ((size_t)img*PW + row) * C;
    float2* PZ = (g ? pzb : pza) + ((size_t)img*PW + row) * C;
    int iy = row - R;
    bool rowok = ((unsigned)iy < HWDIM);
    const float* src = inp + (size_t)img*NPIX + (size_t)(rowok ? iy : 0)*HWDIM;
    const int lane = threadIdx.x;
    if (lane == 0) { P0[0] = 0.f; PZ[0] = make_float2(0.f, 0.f); }
    float c0 = 0.f, c1 = 0.f, c2 = 0.f;
    for (int i = 0; i < 6; ++i) {
        int k = i*64 + lane;
        float v = 0.f;
        if (k < PW && rowok) { int ix = k - R; if ((unsigned)ix < HWDIM) v = src[ix]; }
        float xd = (float)k;
        float w0 = v, w1 = v*xd, w2 = v*xd*xd;
        #pragma unroll
        for (int off = 1; off < 64; off <<= 1) {
            float t0 = __shfl_up(w0, off), t1 = __shfl_up(w1, off), t2 = __shfl_up(w2, off);
            if (lane >= off) { w0 += t0; w1 += t1; w2 += t2; }
        }
        if (k < PW) {
            P0[k+1] = c0 + w0;
            PZ[k+1] = make_float2(c1 + w1, c2 + w2);
        }
        c0 += __shfl(w0, 63); c1 += __shfl(w1, 63); c2 += __shfl(w2, 63);
    }
}

// image sums from P0a row-end prefix values (1788 reads instead of 1.2 MB)
__global__ __launch_bounds__(256) void k_sums2(const float* __restrict__ p0a,
        float* __restrict__ sums) {
    int img = blockIdx.x;
    __shared__ float red[256];
    float s = 0.f;
    const int C = PW1v + 1;
    for (int r = threadIdx.x; r < PW1v; r += 256)
        s += p0a[((size_t)img*PW1v + r)*C + PW1v];
    red[threadIdx.x] = s; __syncthreads();
    for (int w = 128; w > 0; w >>= 1) {
        if (threadIdx.x < w) red[threadIdx.x] += red[threadIdx.x + w];
        __syncthreads();
    }
    if (threadIdx.x == 0) sums[img] = red[0];
}

// exact initial K = min(floor(sqrt(X)), R): over-estimate then integer fix-down
__device__ __forceinline__ int k_init_exact(int X, int R) {
    int K = (int)sqrtf((float)X) + 1;
    if (K > R) K = R;
    while (K > 0 && K*K > X) --K;
    return K;
}

// per-lane disc mass over {dy^2+dx^2 <= X, |dy|,|dx| <= R}.
// K maintained incrementally (floor(sqrt(t)) non-increasing as t decreases).
// __all is wave-scoped -> loop trip is the wave-max regardless of block size.
__device__ __forceinline__ float dmass1(int X, const float* __restrict__ P0, int bidx,
        int C, int R) {
    float m = 0.f;
    int K = 0;
    if (X >= 0) {
        K = k_init_exact(X, R);
        m = P0[bidx+K+1] - P0[bidx-K];
    }
    int t = X - 1, step = 3;
    const float* __restrict__ Pu = P0 - C;
    const float* __restrict__ Pd = P0 + C;
    for (int dyy = 1; dyy <= R; ++dyy) {
        if (__all(t < 0)) break;
        if (t >= 0) {
            while (K*K > t) --K;
            int A = bidx + K + 1, B = bidx - K;
            m += (Pu[A] - Pu[B]) + (Pd[A] - Pd[B]);
        }
        t -= step; step += 2; Pu -= C; Pd += C;
    }
    return m;
}

// XCD-pinned (blockIdx%8 -> XCD), 2-wave (128-thread) blocks:
// 16 wg/CU slot limit x 2 waves = up to 32 waves/CU (vs 16 with 1-wave blocks).
//   XCD i<6: g1 field 6+i blocks 0..391 + donated g0 field i blocks 320..391
//   XCD 6,7: g0 fields {0,1,2}/{3,4,5} blocks 0..319 each
__global__ __launch_bounds__(128, 8) void k_dtm(const float* __restrict__ sums,
        const float* __restrict__ p0a, const float2* __restrict__ pza,
        const float* __restrict__ p0b, const float2* __restrict__ pzb,
        float* __restrict__ dt) {
    const int xcd = blockIdx.x & 7, slot = blockIdx.x >> 3;
    int f, blk;
    if (xcd < 6) {
        if (slot < BPF128)               { f = 6 + xcd; blk = slot; }
        else if (slot < BPF128 + DON128) { f = xcd; blk = slot - DON128; }
        else return;
    } else {
        const int per = BPF128 - DON128;  // 320
        if (slot >= 3*per) return;
        int q = slot / per;
        f = (xcd - 6)*3 + q; blk = slot - q*per;
    }
    const int layer = f >> 1, b = f & 1;
    const int g = layer / 3, c = layer % 3;
    const int img = b*3 + c;
    const int R = g ? R2v : R1v, PW = g ? PW2v : PW1v, C = PW + 1;
    const int R2 = 2*R*R;
    const float thr = (g ? 0.2f : 0.05f) * sums[img];
    const float* __restrict__ P0 = (g ? p0b : p0a) + (size_t)img*PW*C;
    const float2* __restrict__ PZ = (g ? pzb : pza) + (size_t)img*PW*C;

    const int p = blk*128 + threadIdx.x;
    const int y = p / HWDIM, x = p % HWDIM;
    const int xc = x + R;
    const int bidx = (y + R)*C + xc;

    // ---- main probes: per-lane bisection; bracket width stops at <= 86/43 ----
    const int NP = g ? 7 : 6;
    const int WSTOP = g ? 86 : 43;
    int lo = 0, hi = R2 + 1;
    for (int it = 0; it < NP; ++it) {
        int X = (lo + hi) >> 1;
        float m = dmass1(X, P0, bidx, C, R);
        if (m >= thr) hi = X; else lo = X + 1;
    }
    // ---- refine for stragglers / non-crossers (exact bracket updates) ----
    for (int rit = 0; rit < 14; ++rit) {
        bool act = (hi == R2 + 1) ? (lo < hi) : (hi - lo > WSTOP);
        if (__all(!act)) break;
        int X = act ? ((lo + hi) >> 1) : -1;
        float m = dmass1(X, P0, bidx, C, R);
        if (X >= 0) { if (m >= thr) hi = X; else lo = X + 1; }
    }
    const bool nr = (hi == R2 + 1);
    const int  Dst = nr ? lo : ((lo + hi) >> 1);
    const bool cross = nr ? (lo <= R2) : true;
    const int  Xin = cross ? (Dst - 1) : R2;

    // ---- weighted pass at Xin: mass_in and wsum_in ----
    float m_in = 0.f, ws = 0.f;
    const float c2n = -2.f * (float)xc;
    const int xc2i = xc * xc;
    int K = 0;
    if (Xin >= 0) {
        K = k_init_exact(Xin, R);
        int A = bidx+K+1, B = bidx-K;
        float s0 = P0[A] - P0[B]; float2 zA = PZ[A], zB = PZ[B];
        m_in += s0; ws += fmaf((float)xc2i, s0, fmaf(c2n, zA.x - zB.x, zA.y - zB.y));
    }
    {
        int t = Xin - 1, step = 3, d2 = 1;
        const float* __restrict__ Pu = P0 - C;
        const float* __restrict__ Pd = P0 + C;
        const float2* __restrict__ Zu = PZ - C;
        const float2* __restrict__ Zd = PZ + C;
        for (int dyy = 1; dyy <= R; ++dyy) {
            if (__all(t < 0)) break;
            if (t >= 0) {
                while (K*K > t) --K;
                int A = bidx+K+1, B = bidx-K;
                float c1 = (float)(d2 + xc2i);
                { float s0 = Pu[A]-Pu[B]; float2 zA = Zu[A], zB = Zu[B];
                  m_in += s0; ws += fmaf(c1, s0, fmaf(c2n, zA.x - zB.x, zA.y - zB.y)); }
                { float s0 = Pd[A]-Pd[B]; float2 zA = Zd[A], zB = Zd[B];
                  m_in += s0; ws += fmaf(c1, s0, fmaf(c2n, zA.x - zB.x, zA.y - zB.y)); }
            }
            t -= step; d2 += step; step += 2;
            Pu -= C; Pd += C; Zu -= C; Zd += C;
        }
    }
    float s = cross ? (ws + (float)Dst * (thr - m_in)) : ws;
    float d = sqrtf(fmaxf(s / thr, 0.f));
    dt[(size_t)f*NPIX + p] = d;
}

// full-GPU steepest descent (keys reconstructed from dt) + per-field min/max
// via atomicMin (max stored as complement so one 0xFF memset inits both).
__global__ __launch_bounds__(256) void k_desc(const float* __restrict__ dt,
        unsigned short* __restrict__ par, u64* __restrict__ gmm) {
    const int f = blockIdx.y;
    const int p = blockIdx.x*256 + threadIdx.x;
    const float* __restrict__ dtf = dt + (size_t)f*NPIX;
    float dc = dtf[p];
    u64 kc = ((u64)__float_as_uint(dc) << 32) | (unsigned)p;
    u64 best = kc; int bi = p;
    const int y = p / HWDIM, x = p % HWDIM;
    if (y > 0)        { float v = dtf[p - HWDIM]; u64 t = ((u64)__float_as_uint(v)<<32)|(unsigned)(p-HWDIM); if (t < best) { best = t; bi = p-HWDIM; } }
    if (y < HWDIM-1)  { float v = dtf[p + HWDIM]; u64 t = ((u64)__float_as_uint(v)<<32)|(unsigned)(p+HWDIM); if (t < best) { best = t; bi = p+HWDIM; } }
    if (x > 0)        { float v = dtf[p - 1];     u64 t = ((u64)__float_as_uint(v)<<32)|(unsigned)(p-1);     if (t < best) { best = t; bi = p-1; } }
    if (x < HWDIM-1)  { float v = dtf[p + 1];     u64 t = ((u64)__float_as_uint(v)<<32)|(unsigned)(p+1);     if (t < best) { best = t; bi = p+1; } }
    par[(size_t)f*NPIX + p] = (unsigned short)bi;
    __shared__ u64 rmin[256], rmax[256];
    u64 mk = ((u64)__float_as_uint(dc) << 32) | (unsigned)(0xFFFF - p);
    rmin[threadIdx.x] = kc; rmax[threadIdx.x] = mk;
    __syncthreads();
    for (int w = 128; w > 0; w >>= 1) {
        if (threadIdx.x < w) {
            if (rmin[threadIdx.x + w] < rmin[threadIdx.x]) rmin[threadIdx.x] = rmin[threadIdx.x + w];
            if (rmax[threadIdx.x + w] > rmax[threadIdx.x]) rmax[threadIdx.x] = rmax[threadIdx.x + w];
        }
        __syncthreads();
    }
    if (threadIdx.x == 0) {
        atomicMin(&gmm[f*2 + 0], rmin[0]);
        atomicMin(&gmm[f*2 + 1], ~rmax[0]);
    }
}

// per-field: LDS pointer-jump the parent forest, write roots back to global par.
__global__ __launch_bounds__(1024) void k_root(unsigned short* __restrict__ parg) {
    const int f = blockIdx.x;
    const int tid = threadIdx.x; const int bs = 1024;
    __shared__ unsigned short par[NPIX];   // 100,352 B
    {
        const unsigned* src = (const unsigned*)(parg + (size_t)f*NPIX);
        unsigned* dst = (unsigned*)par;
        for (int i = tid; i < NPIX/2; i += bs) dst[i] = src[i];
    }
    __syncthreads();
    for (int pass = 0; pass < 6; ++pass) {
        for (int p = tid; p < NPIX; p += bs) par[p] = par[par[p]];
        __syncthreads();
    }
    for (int p = tid; p < NPIX; p += bs) {
        int a = par[p];
        int n = par[a];
        while (n != a) { a = n; n = par[a]; }
        par[p] = (unsigned short)a;
    }
    __syncthreads();
    {
        const unsigned* src = (const unsigned*)par;
        unsigned* dst = (unsigned*)(parg + (size_t)f*NPIX);
        for (int i = tid; i < NPIX/2; i += bs) dst[i] = src[i];
    }
}

__device__ inline unsigned hash64(u64 x) {
    x ^= x >> 33; x *= 0xff51afd7ed558ccdULL;
    x ^= x >> 33; x *= 0xc4ceb9fe1a85ec53ULL;
    x ^= x >> 33;
    return (unsigned)x;
}

// full-GPU edge extraction: roots + dt -> dedup'd pair hash with min death key.
__global__ __launch_bounds__(256) void k_edges(const float* __restrict__ dt,
        const unsigned short* __restrict__ parg,
        u64* __restrict__ hpair, u64* __restrict__ hbest) {
    const int f = blockIdx.y;
    const int p = blockIdx.x*256 + threadIdx.x;
    const float* __restrict__ dtf = dt + (size_t)f*NPIX;
    const unsigned short* __restrict__ par = parg + (size_t)f*NPIX;
    u64* hp = hpair + (size_t)f*HSIZE;
    u64* hb = hbest + (size_t)f*HSIZE;
    const int rp = par[p];
    const int y = p / HWDIM, x = p % HWDIM;
    const float dp = dtf[p];
    #pragma unroll
    for (int e = 0; e < 2; ++e) {
        int q;
        if (e == 0) { if (x >= HWDIM-1) continue; q = p + 1; }
        else        { if (y >= HWDIM-1) continue; q = p + HWDIM; }
        int rq = par[q];
        if (rq == rp) continue;
        float dq = dtf[q];
        bool pdies = (dp > dq) || (dp == dq && p > q);
        u64 ekv = pdies
            ? (((u64)__float_as_uint(dp) << 32) | ((u64)(unsigned)p << 16) | (unsigned)rp)
            : (((u64)__float_as_uint(dq) << 32) | ((u64)(unsigned)q << 16) | (unsigned)rq);
        int ra = min(rp, rq), rb = max(rp, rq);
        u64 pk = ((u64)(unsigned)ra << 32) | (unsigned)rb;
        unsigned h = hash64(pk) & (HSIZE - 1);
        for (int probe = 0; probe < HSIZE; ++probe) {
            u64 old = atomicCAS(&hp[h], ~0ull, pk);
            if (old == ~0ull || old == pk) { atomicMin(&hb[h], ekv); break; }
            h = (h + 1) & (HSIZE - 1);
        }
    }
}

__device__ __forceinline__ void bitonic_n(u64* ek, int tid, int n, int bst) {
    for (int k = 2; k <= n; k <<= 1) {
        for (int j = k >> 1; j > 0; j >>= 1) {
            for (int i = tid; i < n; i += bst) {
                int ixj = i ^ j;
                if (ixj > i) {
                    u64 a = ek[i], b = ek[ixj];
                    if (((i & k) == 0) ? (a > b) : (a < b)) { ek[i] = b; ek[ixj] = a; }
                }
            }
            __syncthreads();
        }
    }
}

// per-field finish: hash compaction + Kruskal + top-64 + tent features.
__global__ __launch_bounds__(1024) void k_finish(const float* __restrict__ dt,
        const u64* __restrict__ gmm,
        const u64* __restrict__ hpair, const u64* __restrict__ hbest,
        LayerParams lp, float* __restrict__ xbuf) {
    const int f = blockIdx.x;
    const int layer = f >> 1, bb = f & 1;
    const int tid = threadIdx.x; const int bs = 1024;
    const float* dtf = dt + (size_t)f*NPIX;
    const u64* hp = hpair + (size_t)f*HSIZE;
    const u64* hb = hbest + (size_t)f*HSIZE;

    __shared__ u64 ek[FCAP];
    __shared__ unsigned int epk[FCAP];
    __shared__ unsigned int eab[FCAP];
    __shared__ unsigned short eru[FCAP];
    __shared__ int rhk[RHASH];
    __shared__ short ufp[RHASH];
    __shared__ float rdt[RHASH];
    __shared__ unsigned int pyd[FCAP];
    __shared__ float ppr[FCAP];
    __shared__ float birth[64], death[64], featsh[2*TT];
    __shared__ int spec_a[64], spec_b[64];
    __shared__ u64 spec_e[64];
    __shared__ int cnt_s, pc_s;
    __shared__ int gmin_s, gmax_s; __shared__ float gminf_s, gmaxf_s;

    if (tid == 0) {
        u64 g0v = gmm[f*2 + 0];
        u64 g1v = ~gmm[f*2 + 1];
        gmin_s = (int)(unsigned)(g0v & 0xFFFFFFFFu);
        gminf_s = __uint_as_float((unsigned)(g0v >> 32));
        gmax_s = 0xFFFF - (int)(g1v & 0xFFFFu);
        gmaxf_s = __uint_as_float((unsigned)(g1v >> 32));
        cnt_s = 0; pc_s = 0;
    }
    for (int i = tid; i < RHASH; i += bs) rhk[i] = -1;
    __syncthreads();
    // ---- Phase A: compact edge hash into LDS + dense root hash ----
    for (int i = tid; i < HSIZE; i += bs) {
        u64 pk = hp[i];
        if (pk != ~0ull) {
            int slot2 = atomicAdd(&cnt_s, 1);
            if (slot2 < FCAP) {
                u64 e = hb[i];
                unsigned u = (unsigned)((e >> 16) & 0xFFFFu);
                unsigned ru = (unsigned)(e & 0xFFFFu);
                ek[slot2] = (e & 0xFFFFFFFF00000000ull) | ((u64)u << 16) | (unsigned)slot2;
                int ra = (int)(pk >> 32), rb = (int)(pk & 0xFFFFFFFFu);
                epk[slot2] = ((unsigned)ra << 16) | (unsigned)rb;
                eru[slot2] = (unsigned short)ru;
                #pragma unroll
                for (int pass = 0; pass < 2; ++pass) {
                    int r = pass ? rb : ra;
                    unsigned h = ((unsigned)r * 2654435761u) & (RHASH - 1);
                    for (int pr = 0; pr < RHASH; ++pr) {
                        int old = atomicCAS(&rhk[h], -1, r);
                        if (old == -1 || old == r) break;
                        h = (h + 1) & (RHASH - 1);
                    }
                }
            }
        }
    }
    __syncthreads();
    int cnt = min(cnt_s, FCAP);
    int n1 = 64; while (n1 < cnt) n1 <<= 1;
    // ---- Phase B: per-edge UF slot resolve (parallel) ----
    for (int s2 = tid; s2 < cnt; s2 += bs) {
        unsigned pk2 = epk[s2];
        int ra = (int)(pk2 >> 16), rb = (int)(pk2 & 0xFFFFu);
        int ru = eru[s2];
        int rv = (ru == ra) ? rb : ra;
        int su = -1, sv = -1;
        { unsigned h = ((unsigned)ru * 2654435761u) & (RHASH - 1);
          for (int pr = 0; pr < RHASH; ++pr) { int v = rhk[h]; if (v == ru) { su = (int)h; break; } if (v == -1) break; h = (h + 1) & (RHASH - 1); } }
        { unsigned h = ((unsigned)rv * 2654435761u) & (RHASH - 1);
          for (int pr = 0; pr < RHASH; ++pr) { int v = rhk[h]; if (v == rv) { sv = (int)h; break; } if (v == -1) break; h = (h + 1) & (RHASH - 1); } }
        eab[s2] = ((unsigned)su << 16) | (unsigned)(sv & 0xFFFF);
    }
    for (int i = cnt + tid; i < n1; i += bs) ek[i] = ~0ull;
    for (int s2 = tid; s2 < RHASH; s2 += bs) {
        ufp[s2] = (short)s2;
        int r = rhk[s2];
        rdt[s2] = (r >= 0) ? dtf[r] : 0.f;
    }
    __syncthreads();

    bitonic_n(ek, tid, n1, bs);   // ascending (death dt, death pixel, slot)

    // ---- Kruskal (elder rule): wave-speculative find + lane-0 serial apply ----
    if (tid < 64) {
        int pc = 0;
        for (int base = 0; base < cnt; base += 64) {
            int i = base + tid;
            int sa = -1, sb = -1; u64 e = ~0ull;
            if (i < cnt) {
                e = ek[i];
                int idx = (int)(e & 0xFFFFu);
                unsigned ab = eab[idx];
                sa = (int)(ab >> 16); sb = (int)(ab & 0xFFFFu);
                if (sa != 0xFFFF && sb != 0xFFFF) {
                    while (ufp[sa] != sa) { short g2 = ufp[ufp[sa]]; ufp[sa] = g2; sa = g2; }
                    while (ufp[sb] != sb) { short g2 = ufp[ufp[sb]]; ufp[sb] = g2; sb = g2; }
                    if (sa == sb) sa = -1;      // already connected: sound skip
                } else { sa = -1; }
            }
            spec_a[tid] = sa; spec_b[tid] = sb; spec_e[tid] = e;
            if (tid == 0) {
                int lim = min(64, cnt - base);
                for (int j = 0; j < lim; ++j) {
                    int sa2 = spec_a[j];
                    if (sa2 < 0) continue;
                    int sb2 = spec_b[j];
                    u64 e2 = spec_e[j];
                    while (ufp[sa2] != sa2) { short g2 = ufp[ufp[sa2]]; ufp[sa2] = g2; sa2 = g2; }
                    while (ufp[sb2] != sb2) { short g2 = ufp[ufp[sb2]]; ufp[sb2] = g2; sb2 = g2; }
                    if (sa2 == sb2) continue;
                    float fa = rdt[sa2], fb = rdt[sb2];
                    int elder, young;
                    if (fa <= fb) { elder = sa2; young = sb2; } else { elder = sb2; young = sa2; }
                    ufp[young] = (short)elder;
                    float pers = __uint_as_float((unsigned)(e2 >> 32)) - rdt[young];
                    if (pers > 0.f && pc < FCAP - 1) {
                        int u = (int)((e2 >> 16) & 0xFFFFu);
                        pyd[pc] = ((unsigned)rhk[young] << 16) | (unsigned)u;
                        ppr[pc] = pers; ++pc;
                    }
                }
            }
        }
        if (tid == 0) {
            pyd[pc] = ((unsigned)gmin_s << 16) | (unsigned)gmax_s;
            ppr[pc] = gmaxf_s - gminf_s; ++pc;
            pc_s = pc;
        }
    }
    __syncthreads();
    const int pc = pc_s;
    int n2 = 64; while (n2 < pc) n2 <<= 1;

    // ---- top-64 by persistence (descending via ~persbits) ----
    for (int i = tid; i < n2; i += bs) {
        if (i < pc && ppr[i] > 0.f)
            ek[i] = ((u64)(0xFFFFFFFFu - __float_as_uint(ppr[i])) << 32) | (unsigned)i;
        else ek[i] = ~0ull;
    }
    __syncthreads();
    bitonic_n(ek, tid, n2, bs);
    if (tid < 64) {
        u64 e = ek[tid];
        int bpix = 0, dpix = 0, msk = 0;
        if (e != ~0ull) {
            int i = (int)(e & 0xFFFFFFFFu);
            unsigned pd2 = pyd[i];
            bpix = (int)(pd2 >> 16); dpix = (int)(pd2 & 0xFFFFu); msk = 1;
        }
        float bv = dtf[bpix];
        float dv = msk ? dtf[dpix] : bv;
        birth[tid] = bv; death[tid] = dv;
    }
    __syncthreads();
    if (tid < TT) {
        float t = lp.tseq[layer][tid];
        float m1 = 0.f, m2 = 0.f;
        for (int m = 0; m < 64; ++m) {
            float v = fmaxf(fminf(t - birth[m], death[m] - t), 0.f);
            if (v > m1) { m2 = m1; m1 = v; } else if (v > m2) m2 = v;
        }
        featsh[tid] = m1; featsh[TT + tid] = m2;
    }
    __syncthreads();
    if (tid < 50) {
        const float* w = lp.gw[layer] + tid * 50;
        float acc = lp.gb[layer][tid];
        #pragma unroll
        for (int j = 0; j < 50; ++j) acc = fmaf(featsh[j], w[j], acc);
        xbuf[bb*300 + layer*50 + tid] = acc;
    }
}

__global__ __launch_bounds__(512) void k_final(const float* __restrict__ x, const float* __restrict__ fcw,
        const float* __restrict__ fcb, float* __restrict__ out) {
    __shared__ float rl[2][300];
    const int tid = threadIdx.x;
    if (tid < 300) {
        float a0 = x[tid], a1 = x[300 + tid];
        out[14 + tid] = fabsf(a0) + fabsf(a1);
        rl[0][tid] = fmaxf(a0, 0.f);
        rl[1][tid] = fmaxf(a1, 0.f);
    }
    __syncthreads();
    if (tid < 14) {
        int b = tid / 7, i = tid % 7;
        float acc = fcb[i];
        const float* w = fcw + i * 300;
        for (int j = 0; j < 300; ++j) acc = fmaf(rl[b][j], w[j], acc);
        out[b*7 + i] = acc;
    }
}

// ---------------- host ----------------
extern "C" void kernel_launch(void* const* d_in, const int* in_sizes, int n_in,
                              void* d_out, int out_size, void* d_ws, size_t ws_size,
                              hipStream_t stream) {
    (void)in_sizes; (void)n_in; (void)out_size; (void)ws_size;
    const float* inp = (const float*)d_in[0];
    LayerParams lp;
    for (int l = 0; l < 6; ++l) {
        lp.tseq[l] = (const float*)d_in[1 + 3*l];
        lp.gw[l]   = (const float*)d_in[2 + 3*l];
        lp.gb[l]   = (const float*)d_in[3 + 3*l];
    }
    const float* fcw = (const float*)d_in[19];
    const float* fcb = (const float*)d_in[20];

    char* w = (char*)d_ws;
    float* sums = (float*)(w + OFF_SUMS);
    float* p0a = (float*)(w + OFF_P0A);
    float2* pza = (float2*)(w + OFF_PZA);
    float* p0b = (float*)(w + OFF_P0B);
    float2* pzb = (float2*)(w + OFF_PZB);
    float* dt = (float*)(w + OFF_DT);
    unsigned short* par = (unsigned short*)(w + OFF_PAR);
    u64* hp = (u64*)(w + OFF_HP);
    u64* hb = (u64*)(w + OFF_HB);
    u64* gmm = (u64*)(w + OFF_GMM);
    float* xbuf = (float*)(w + OFF_X);

    const int prefRows = 6*PW1v + 6*PW2v;
    hipLaunchKernelGGL(k_prefix, dim3(prefRows), dim3(64), 0, stream,
                       inp, p0a, pza, p0b, pzb);
    hipLaunchKernelGGL(k_sums2, dim3(6), dim3(256), 0, stream, p0a, sums);
    hipMemsetAsync(hp, 0xFF, (size_t)2*NFIELD*HSIZE*8 + 256, stream);
    const int maxslot = 3 * (BPF128 - DON128);   // 960
    hipLaunchKernelGGL(k_dtm, dim3(8 * maxslot), dim3(128), 0, stream,
                       sums, p0a, pza, p0b, pzb, dt);
    hipLaunchKernelGGL(k_desc, dim3(NPIX/256, NFIELD), dim3(256), 0, stream, dt, par, gmm);
    hipLaunchKernelGGL(k_root, dim3(NFIELD), dim3(1024), 0, stream, par);
    hipLaunchKernelGGL(k_edges, dim3(NPIX/256, NFIELD), dim3(256), 0, stream, dt, par, hp, hb);
    hipLaunchKernelGGL(k_finish, dim3(NFIELD), dim3(1024), 0, stream, dt, gmm, hp, hb, lp, xbuf);
    hipLaunchKernelGGL(k_final, dim3(1), dim3(512), 0, stream, xbuf, fcw, fcb, (float*)d_out);
}

// Round 19
// 653.735 us; speedup vs baseline: 1.0498x; 1.0498x over previous
//
#include <hip/hip_runtime.h>
#include <stdint.h>

#define HWDIM 224
#define NPIX (HWDIM*HWDIM)
#define NFIELD 12
#define TT 25

#define R1v 37
#define PW1v (HWDIM + 2*R1v)        /* 298 */
#define R2v 74
#define PW2v (HWDIM + 2*R2v)        /* 372 */

#define HSIZE 16384
#define FCAP 4096
#define RHASH 4096
#define DON64 144                   /* g0 64-px blocks donated to each g1 XCD */
#define BPF 784                     /* 64-px blocks per field */

typedef unsigned long long u64;

struct LayerParams {
    const float* tseq[6];
    const float* gw[6];
    const float* gb[6];
};

// ---------------- workspace layout ----------------
constexpr size_t alup(size_t x) { return (x + 255) & ~(size_t)255; }
constexpr size_t SZPA = (size_t)6*PW1v*(PW1v+1)*4;
constexpr size_t SZPB = (size_t)6*PW2v*(PW2v+1)*4;
constexpr size_t OFF_SUMS = 0;
constexpr size_t OFF_P0A = alup(OFF_SUMS + 8*4);
constexpr size_t OFF_PZA = alup(OFF_P0A + SZPA);      // float2 (P1,P2)
constexpr size_t OFF_P0B = alup(OFF_PZA + 2*SZPA);
constexpr size_t OFF_PZB = alup(OFF_P0B + SZPB);
constexpr size_t OFF_DT   = alup(OFF_PZB + 2*SZPB);
constexpr size_t OFF_PAR  = alup(OFF_DT   + (size_t)NFIELD*NPIX*4);
constexpr size_t OFF_HP   = alup(OFF_PAR  + (size_t)NFIELD*NPIX*2);
constexpr size_t OFF_HB   = alup(OFF_HP   + (size_t)NFIELD*HSIZE*8);   // contiguous with HP
constexpr size_t OFF_GMM  = OFF_HB + (size_t)NFIELD*HSIZE*8;           // contiguous (0xFF memset)
constexpr size_t OFF_X    = alup(OFF_GMM + 256);

// ---------------- kernels ----------------

// f32 accumulation (reference itself uses f32 cumsum; error negligible vs 0.24).
__global__ __launch_bounds__(64) void k_prefix(const float* __restrict__ inp,
        float* __restrict__ p0a, float2* __restrict__ pza,
        float* __restrict__ p0b, float2* __restrict__ pzb) {
    int bidx = blockIdx.x;
    const int tot0 = 6 * PW1v;
    int g = (bidx >= tot0);
    int rem = g ? (bidx - tot0) : bidx;
    const int PW = g ? PW2v : PW1v, R = g ? R2v : R1v, C = PW + 1;
    int img = rem / PW, row = rem % PW;
    float* P0 = (g ? p0b : p0a) + ((size_t)img*PW + row) * C;
    float2* PZ = (g ? pzb : pza) + ((size_t)img*PW + row) * C;
    int iy = row - R;
    bool rowok = ((unsigned)iy < HWDIM);
    const float* src = inp + (size_t)img*NPIX + (size_t)(rowok ? iy : 0)*HWDIM;
    const int lane = threadIdx.x;
    if (lane == 0) { P0[0] = 0.f; PZ[0] = make_float2(0.f, 0.f); }
    float c0 = 0.f, c1 = 0.f, c2 = 0.f;
    for (int i = 0; i < 6; ++i) {
        int k = i*64 + lane;
        float v = 0.f;
        if (k < PW && rowok) { int ix = k - R; if ((unsigned)ix < HWDIM) v = src[ix]; }
        float xd = (float)k;
        float w0 = v, w1 = v*xd, w2 = v*xd*xd;
        #pragma unroll
        for (int off = 1; off < 64; off <<= 1) {
            float t0 = __shfl_up(w0, off), t1 = __shfl_up(w1, off), t2 = __shfl_up(w2, off);
            if (lane >= off) { w0 += t0; w1 += t1; w2 += t2; }
        }
        if (k < PW) {
            P0[k+1] = c0 + w0;
            PZ[k+1] = make_float2(c1 + w1, c2 + w2);
        }
        c0 += __shfl(w0, 63); c1 += __shfl(w1, 63); c2 += __shfl(w2, 63);
    }
}

// image sums from P0a row-end prefix values (1788 reads instead of 1.2 MB)
__global__ __launch_bounds__(256) void k_sums2(const float* __restrict__ p0a,
        float* __restrict__ sums) {
    int img = blockIdx.x;
    __shared__ float red[256];
    float s = 0.f;
    const int C = PW1v + 1;
    for (int r = threadIdx.x; r < PW1v; r += 256)
        s += p0a[((size_t)img*PW1v + r)*C + PW1v];
    red[threadIdx.x] = s; __syncthreads();
    for (int w = 128; w > 0; w >>= 1) {
        if (threadIdx.x < w) red[threadIdx.x] += red[threadIdx.x + w];
        __syncthreads();
    }
    if (threadIdx.x == 0) sums[img] = red[0];
}

// exact initial K = min(floor(sqrt(X)), R): over-estimate then integer fix-down
__device__ __forceinline__ int k_init_exact(int X, int R) {
    int K = (int)sqrtf((float)X) + 1;
    if (K > R) K = R;
    while (K > 0 && K*K > X) --K;
    return K;
}

// per-lane disc mass over {dy^2+dx^2 <= X, |dy|,|dx| <= R}.
// K maintained incrementally (floor(sqrt(t)) non-increasing as t decreases).
__device__ __forceinline__ float dmass1(int X, const float* __restrict__ P0, int bidx,
        int C, int R) {
    float m = 0.f;
    int K = 0;
    if (X >= 0) {
        K = k_init_exact(X, R);
        m = P0[bidx+K+1] - P0[bidx-K];
    }
    int t = X - 1, step = 3;
    const float* __restrict__ Pu = P0 - C;
    const float* __restrict__ Pd = P0 + C;
    for (int dyy = 1; dyy <= R; ++dyy) {
        if (__all(t < 0)) break;
        if (t >= 0) {
            while (K*K > t) --K;
            int A = bidx + K + 1, B = bidx - K;
            m += (Pu[A] - Pu[B]) + (Pd[A] - Pd[B]);
        }
        t -= step; step += 2; Pu -= C; Pd += C;
    }
    return m;
}

// XCD-pinned (blockIdx%8 -> XCD), single-WAVE blocks for fine-grained packing:
//   XCD i<6: g1 field 6+i blocks 0..783 + donated g0 field i blocks 640..783
//   XCD 6,7: g0 fields {0,1,2}/{3,4,5} blocks 0..639 each
__global__ __launch_bounds__(64) void k_dtm(const float* __restrict__ sums,
        const float* __restrict__ p0a, const float2* __restrict__ pza,
        const float* __restrict__ p0b, const float2* __restrict__ pzb,
        float* __restrict__ dt) {
    const int xcd = blockIdx.x & 7, slot = blockIdx.x >> 3;
    int f, blk;
    if (xcd < 6) {
        if (slot < BPF)              { f = 6 + xcd; blk = slot; }
        else if (slot < BPF + DON64) { f = xcd; blk = slot - DON64; }
        else return;
    } else {
        const int per = BPF - DON64;  // 640
        if (slot >= 3*per) return;
        int q = slot / per;
        f = (xcd - 6)*3 + q; blk = slot - q*per;
    }
    const int layer = f >> 1, b = f & 1;
    const int g = layer / 3, c = layer % 3;
    const int img = b*3 + c;
    const int R = g ? R2v : R1v, PW = g ? PW2v : PW1v, C = PW + 1;
    const int R2 = 2*R*R;
    const float thr = (g ? 0.2f : 0.05f) * sums[img];
    const float* __restrict__ P0 = (g ? p0b : p0a) + (size_t)img*PW*C;
    const float2* __restrict__ PZ = (g ? pzb : pza) + (size_t)img*PW*C;

    const int p = blk*64 + threadIdx.x;
    const int y = p / HWDIM, x = p % HWDIM;
    const int xc = x + R;
    const int bidx = (y + R)*C + xc;

    // ---- main probes: per-lane bisection; bracket width stops at <= 86/43 ----
    const int NP = g ? 7 : 6;
    const int WSTOP = g ? 86 : 43;
    int lo = 0, hi = R2 + 1;
    for (int it = 0; it < NP; ++it) {
        int X = (lo + hi) >> 1;
        float m = dmass1(X, P0, bidx, C, R);
        if (m >= thr) hi = X; else lo = X + 1;
    }
    // ---- refine for stragglers / non-crossers (exact bracket updates) ----
    for (int rit = 0; rit < 14; ++rit) {
        bool act = (hi == R2 + 1) ? (lo < hi) : (hi - lo > WSTOP);
        if (__all(!act)) break;
        int X = act ? ((lo + hi) >> 1) : -1;
        float m = dmass1(X, P0, bidx, C, R);
        if (X >= 0) { if (m >= thr) hi = X; else lo = X + 1; }
    }
    const bool nr = (hi == R2 + 1);
    const int  Dst = nr ? lo : ((lo + hi) >> 1);
    const bool cross = nr ? (lo <= R2) : true;
    const int  Xin = cross ? (Dst - 1) : R2;

    // ---- weighted pass at Xin: mass_in and wsum_in ----
    float m_in = 0.f, ws = 0.f;
    const float c2n = -2.f * (float)xc;
    const int xc2i = xc * xc;
    int K = 0;
    if (Xin >= 0) {
        K = k_init_exact(Xin, R);
        int A = bidx+K+1, B = bidx-K;
        float s0 = P0[A] - P0[B]; float2 zA = PZ[A], zB = PZ[B];
        m_in += s0; ws += fmaf((float)xc2i, s0, fmaf(c2n, zA.x - zB.x, zA.y - zB.y));
    }
    {
        int t = Xin - 1, step = 3, d2 = 1;
        const float* __restrict__ Pu = P0 - C;
        const float* __restrict__ Pd = P0 + C;
        const float2* __restrict__ Zu = PZ - C;
        const float2* __restrict__ Zd = PZ + C;
        for (int dyy = 1; dyy <= R; ++dyy) {
            if (__all(t < 0)) break;
            if (t >= 0) {
                while (K*K > t) --K;
                int A = bidx+K+1, B = bidx-K;
                float c1 = (float)(d2 + xc2i);
                { float s0 = Pu[A]-Pu[B]; float2 zA = Zu[A], zB = Zu[B];
                  m_in += s0; ws += fmaf(c1, s0, fmaf(c2n, zA.x - zB.x, zA.y - zB.y)); }
                { float s0 = Pd[A]-Pd[B]; float2 zA = Zd[A], zB = Zd[B];
                  m_in += s0; ws += fmaf(c1, s0, fmaf(c2n, zA.x - zB.x, zA.y - zB.y)); }
            }
            t -= step; d2 += step; step += 2;
            Pu -= C; Pd += C; Zu -= C; Zd += C;
        }
    }
    float s = cross ? (ws + (float)Dst * (thr - m_in)) : ws;
    float d = sqrtf(fmaxf(s / thr, 0.f));
    dt[(size_t)f*NPIX + p] = d;
}

// full-GPU steepest descent (keys reconstructed from dt) + per-field min/max
// via atomicMin (max stored as complement so one 0xFF memset inits both).
__global__ __launch_bounds__(256) void k_desc(const float* __restrict__ dt,
        unsigned short* __restrict__ par, u64* __restrict__ gmm) {
    const int f = blockIdx.y;
    const int p = blockIdx.x*256 + threadIdx.x;
    const float* __restrict__ dtf = dt + (size_t)f*NPIX;
    float dc = dtf[p];
    u64 kc = ((u64)__float_as_uint(dc) << 32) | (unsigned)p;
    u64 best = kc; int bi = p;
    const int y = p / HWDIM, x = p % HWDIM;
    if (y > 0)        { float v = dtf[p - HWDIM]; u64 t = ((u64)__float_as_uint(v)<<32)|(unsigned)(p-HWDIM); if (t < best) { best = t; bi = p-HWDIM; } }
    if (y < HWDIM-1)  { float v = dtf[p + HWDIM]; u64 t = ((u64)__float_as_uint(v)<<32)|(unsigned)(p+HWDIM); if (t < best) { best = t; bi = p+HWDIM; } }
    if (x > 0)        { float v = dtf[p - 1];     u64 t = ((u64)__float_as_uint(v)<<32)|(unsigned)(p-1);     if (t < best) { best = t; bi = p-1; } }
    if (x < HWDIM-1)  { float v = dtf[p + 1];     u64 t = ((u64)__float_as_uint(v)<<32)|(unsigned)(p+1);     if (t < best) { best = t; bi = p+1; } }
    par[(size_t)f*NPIX + p] = (unsigned short)bi;
    __shared__ u64 rmin[256], rmax[256];
    u64 mk = ((u64)__float_as_uint(dc) << 32) | (unsigned)(0xFFFF - p);
    rmin[threadIdx.x] = kc; rmax[threadIdx.x] = mk;
    __syncthreads();
    for (int w = 128; w > 0; w >>= 1) {
        if (threadIdx.x < w) {
            if (rmin[threadIdx.x + w] < rmin[threadIdx.x]) rmin[threadIdx.x] = rmin[threadIdx.x + w];
            if (rmax[threadIdx.x + w] > rmax[threadIdx.x]) rmax[threadIdx.x] = rmax[threadIdx.x + w];
        }
        __syncthreads();
    }
    if (threadIdx.x == 0) {
        atomicMin(&gmm[f*2 + 0], rmin[0]);
        atomicMin(&gmm[f*2 + 1], ~rmax[0]);
    }
}

// per-field: LDS pointer-jump the parent forest, write roots back to global par.
__global__ __launch_bounds__(1024) void k_root(unsigned short* __restrict__ parg) {
    const int f = blockIdx.x;
    const int tid = threadIdx.x; const int bs = 1024;
    __shared__ unsigned short par[NPIX];   // 100,352 B
    {
        const unsigned* src = (const unsigned*)(parg + (size_t)f*NPIX);
        unsigned* dst = (unsigned*)par;
        for (int i = tid; i < NPIX/2; i += bs) dst[i] = src[i];
    }
    __syncthreads();
    for (int pass = 0; pass < 6; ++pass) {
        for (int p = tid; p < NPIX; p += bs) par[p] = par[par[p]];
        __syncthreads();
    }
    for (int p = tid; p < NPIX; p += bs) {
        int a = par[p];
        int n = par[a];
        while (n != a) { a = n; n = par[a]; }
        par[p] = (unsigned short)a;
    }
    __syncthreads();
    {
        const unsigned* src = (const unsigned*)par;
        unsigned* dst = (unsigned*)(parg + (size_t)f*NPIX);
        for (int i = tid; i < NPIX/2; i += bs) dst[i] = src[i];
    }
}

__device__ inline unsigned hash64(u64 x) {
    x ^= x >> 33; x *= 0xff51afd7ed558ccdULL;
    x ^= x >> 33; x *= 0xc4ceb9fe1a85ec53ULL;
    x ^= x >> 33;
    return (unsigned)x;
}

// full-GPU edge extraction: roots + dt -> dedup'd pair hash with min death key.
__global__ __launch_bounds__(256) void k_edges(const float* __restrict__ dt,
        const unsigned short* __restrict__ parg,
        u64* __restrict__ hpair, u64* __restrict__ hbest) {
    const int f = blockIdx.y;
    const int p = blockIdx.x*256 + threadIdx.x;
    const float* __restrict__ dtf = dt + (size_t)f*NPIX;
    const unsigned short* __restrict__ par = parg + (size_t)f*NPIX;
    u64* hp = hpair + (size_t)f*HSIZE;
    u64* hb = hbest + (size_t)f*HSIZE;
    const int rp = par[p];
    const int y = p / HWDIM, x = p % HWDIM;
    const float dp = dtf[p];
    #pragma unroll
    for (int e = 0; e < 2; ++e) {
        int q;
        if (e == 0) { if (x >= HWDIM-1) continue; q = p + 1; }
        else        { if (y >= HWDIM-1) continue; q = p + HWDIM; }
        int rq = par[q];
        if (rq == rp) continue;
        float dq = dtf[q];
        bool pdies = (dp > dq) || (dp == dq && p > q);
        u64 ekv = pdies
            ? (((u64)__float_as_uint(dp) << 32) | ((u64)(unsigned)p << 16) | (unsigned)rp)
            : (((u64)__float_as_uint(dq) << 32) | ((u64)(unsigned)q << 16) | (unsigned)rq);
        int ra = min(rp, rq), rb = max(rp, rq);
        u64 pk = ((u64)(unsigned)ra << 32) | (unsigned)rb;
        unsigned h = hash64(pk) & (HSIZE - 1);
        for (int probe = 0; probe < HSIZE; ++probe) {
            u64 old = atomicCAS(&hp[h], ~0ull, pk);
            if (old == ~0ull || old == pk) { atomicMin(&hb[h], ekv); break; }
            h = (h + 1) & (HSIZE - 1);
        }
    }
}

__device__ __forceinline__ void bitonic_n(u64* ek, int tid, int n, int bst) {
    for (int k = 2; k <= n; k <<= 1) {
        for (int j = k >> 1; j > 0; j >>= 1) {
            for (int i = tid; i < n; i += bst) {
                int ixj = i ^ j;
                if (ixj > i) {
                    u64 a = ek[i], b = ek[ixj];
                    if (((i & k) == 0) ? (a > b) : (a < b)) { ek[i] = b; ek[ixj] = a; }
                }
            }
            __syncthreads();
        }
    }
}

// per-field finish: hash compaction + Kruskal + top-64 + tent features.
__global__ __launch_bounds__(1024) void k_finish(const float* __restrict__ dt,
        const u64* __restrict__ gmm,
        const u64* __restrict__ hpair, const u64* __restrict__ hbest,
        LayerParams lp, float* __restrict__ xbuf) {
    const int f = blockIdx.x;
    const int layer = f >> 1, bb = f & 1;
    const int tid = threadIdx.x; const int bs = 1024;
    const float* dtf = dt + (size_t)f*NPIX;
    const u64* hp = hpair + (size_t)f*HSIZE;
    const u64* hb = hbest + (size_t)f*HSIZE;

    __shared__ u64 ek[FCAP];
    __shared__ unsigned int epk[FCAP];
    __shared__ unsigned int eab[FCAP];
    __shared__ unsigned short eru[FCAP];
    __shared__ int rhk[RHASH];
    __shared__ short ufp[RHASH];
    __shared__ float rdt[RHASH];
    __shared__ unsigned int pyd[FCAP];
    __shared__ float ppr[FCAP];
    __shared__ float birth[64], death[64], featsh[2*TT];
    __shared__ int spec_a[64], spec_b[64];
    __shared__ u64 spec_e[64];
    __shared__ int cnt_s, pc_s;
    __shared__ int gmin_s, gmax_s; __shared__ float gminf_s, gmaxf_s;

    if (tid == 0) {
        u64 g0v = gmm[f*2 + 0];
        u64 g1v = ~gmm[f*2 + 1];
        gmin_s = (int)(unsigned)(g0v & 0xFFFFFFFFu);
        gminf_s = __uint_as_float((unsigned)(g0v >> 32));
        gmax_s = 0xFFFF - (int)(g1v & 0xFFFFu);
        gmaxf_s = __uint_as_float((unsigned)(g1v >> 32));
        cnt_s = 0; pc_s = 0;
    }
    for (int i = tid; i < RHASH; i += bs) rhk[i] = -1;
    __syncthreads();
    // ---- Phase A: compact edge hash into LDS + dense root hash ----
    for (int i = tid; i < HSIZE; i += bs) {
        u64 pk = hp[i];
        if (pk != ~0ull) {
            int slot2 = atomicAdd(&cnt_s, 1);
            if (slot2 < FCAP) {
                u64 e = hb[i];
                unsigned u = (unsigned)((e >> 16) & 0xFFFFu);
                unsigned ru = (unsigned)(e & 0xFFFFu);
                ek[slot2] = (e & 0xFFFFFFFF00000000ull) | ((u64)u << 16) | (unsigned)slot2;
                int ra = (int)(pk >> 32), rb = (int)(pk & 0xFFFFFFFFu);
                epk[slot2] = ((unsigned)ra << 16) | (unsigned)rb;
                eru[slot2] = (unsigned short)ru;
                #pragma unroll
                for (int pass = 0; pass < 2; ++pass) {
                    int r = pass ? rb : ra;
                    unsigned h = ((unsigned)r * 2654435761u) & (RHASH - 1);
                    for (int pr = 0; pr < RHASH; ++pr) {
                        int old = atomicCAS(&rhk[h], -1, r);
                        if (old == -1 || old == r) break;
                        h = (h + 1) & (RHASH - 1);
                    }
                }
            }
        }
    }
    __syncthreads();
    int cnt = min(cnt_s, FCAP);
    int n1 = 64; while (n1 < cnt) n1 <<= 1;
    // ---- Phase B: per-edge UF slot resolve (parallel) ----
    for (int s2 = tid; s2 < cnt; s2 += bs) {
        unsigned pk2 = epk[s2];
        int ra = (int)(pk2 >> 16), rb = (int)(pk2 & 0xFFFFu);
        int ru = eru[s2];
        int rv = (ru == ra) ? rb : ra;
        int su = -1, sv = -1;
        { unsigned h = ((unsigned)ru * 2654435761u) & (RHASH - 1);
          for (int pr = 0; pr < RHASH; ++pr) { int v = rhk[h]; if (v == ru) { su = (int)h; break; } if (v == -1) break; h = (h + 1) & (RHASH - 1); } }
        { unsigned h = ((unsigned)rv * 2654435761u) & (RHASH - 1);
          for (int pr = 0; pr < RHASH; ++pr) { int v = rhk[h]; if (v == rv) { sv = (int)h; break; } if (v == -1) break; h = (h + 1) & (RHASH - 1); } }
        eab[s2] = ((unsigned)su << 16) | (unsigned)(sv & 0xFFFF);
    }
    for (int i = cnt + tid; i < n1; i += bs) ek[i] = ~0ull;
    for (int s2 = tid; s2 < RHASH; s2 += bs) {
        ufp[s2] = (short)s2;
        int r = rhk[s2];
        rdt[s2] = (r >= 0) ? dtf[r] : 0.f;
    }
    __syncthreads();

    bitonic_n(ek, tid, n1, bs);   // ascending (death dt, death pixel, slot)

    // ---- Kruskal (elder rule): wave-speculative find + lane-0 serial apply ----
    if (tid < 64) {
        int pc = 0;
        for (int base = 0; base < cnt; base += 64) {
            int i = base + tid;
            int sa = -1, sb = -1; u64 e = ~0ull;
            if (i < cnt) {
                e = ek[i];
                int idx = (int)(e & 0xFFFFu);
                unsigned ab = eab[idx];
                sa = (int)(ab >> 16); sb = (int)(ab & 0xFFFFu);
                if (sa != 0xFFFF && sb != 0xFFFF) {
                    while (ufp[sa] != sa) { short g2 = ufp[ufp[sa]]; ufp[sa] = g2; sa = g2; }
                    while (ufp[sb] != sb) { short g2 = ufp[ufp[sb]]; ufp[sb] = g2; sb = g2; }
                    if (sa == sb) sa = -1;      // already connected: sound skip
                } else { sa = -1; }
            }
            spec_a[tid] = sa; spec_b[tid] = sb; spec_e[tid] = e;
            if (tid == 0) {
                int lim = min(64, cnt - base);
                for (int j = 0; j < lim; ++j) {
                    int sa2 = spec_a[j];
                    if (sa2 < 0) continue;
                    int sb2 = spec_b[j];
                    u64 e2 = spec_e[j];
                    while (ufp[sa2] != sa2) { short g2 = ufp[ufp[sa2]]; ufp[sa2] = g2; sa2 = g2; }
                    while (ufp[sb2] != sb2) { short g2 = ufp[ufp[sb2]]; ufp[sb2] = g2; sb2 = g2; }
                    if (sa2 == sb2) continue;
                    float fa = rdt[sa2], fb = rdt[sb2];
                    int elder, young;
                    if (fa <= fb) { elder = sa2; young = sb2; } else { elder = sb2; young = sa2; }
                    ufp[young] = (short)elder;
                    float pers = __uint_as_float((unsigned)(e2 >> 32)) - rdt[young];
                    if (pers > 0.f && pc < FCAP - 1) {
                        int u = (int)((e2 >> 16) & 0xFFFFu);
                        pyd[pc] = ((unsigned)rhk[young] << 16) | (unsigned)u;
                        ppr[pc] = pers; ++pc;
                    }
                }
            }
        }
        if (tid == 0) {
            pyd[pc] = ((unsigned)gmin_s << 16) | (unsigned)gmax_s;
            ppr[pc] = gmaxf_s - gminf_s; ++pc;
            pc_s = pc;
        }
    }
    __syncthreads();
    const int pc = pc_s;
    int n2 = 64; while (n2 < pc) n2 <<= 1;

    // ---- top-64 by persistence (descending via ~persbits) ----
    for (int i = tid; i < n2; i += bs) {
        if (i < pc && ppr[i] > 0.f)
            ek[i] = ((u64)(0xFFFFFFFFu - __float_as_uint(ppr[i])) << 32) | (unsigned)i;
        else ek[i] = ~0ull;
    }
    __syncthreads();
    bitonic_n(ek, tid, n2, bs);
    if (tid < 64) {
        u64 e = ek[tid];
        int bpix = 0, dpix = 0, msk = 0;
        if (e != ~0ull) {
            int i = (int)(e & 0xFFFFFFFFu);
            unsigned pd2 = pyd[i];
            bpix = (int)(pd2 >> 16); dpix = (int)(pd2 & 0xFFFFu); msk = 1;
        }
        float bv = dtf[bpix];
        float dv = msk ? dtf[dpix] : bv;
        birth[tid] = bv; death[tid] = dv;
    }
    __syncthreads();
    if (tid < TT) {
        float t = lp.tseq[layer][tid];
        float m1 = 0.f, m2 = 0.f;
        for (int m = 0; m < 64; ++m) {
            float v = fmaxf(fminf(t - birth[m], death[m] - t), 0.f);
            if (v > m1) { m2 = m1; m1 = v; } else if (v > m2) m2 = v;
        }
        featsh[tid] = m1; featsh[TT + tid] = m2;
    }
    __syncthreads();
    if (tid < 50) {
        const float* w = lp.gw[layer] + tid * 50;
        float acc = lp.gb[layer][tid];
        #pragma unroll
        for (int j = 0; j < 50; ++j) acc = fmaf(featsh[j], w[j], acc);
        xbuf[bb*300 + layer*50 + tid] = acc;
    }
}

__global__ __launch_bounds__(512) void k_final(const float* __restrict__ x, const float* __restrict__ fcw,
        const float* __restrict__ fcb, float* __restrict__ out) {
    __shared__ float rl[2][300];
    const int tid = threadIdx.x;
    if (tid < 300) {
        float a0 = x[tid], a1 = x[300 + tid];
        out[14 + tid] = fabsf(a0) + fabsf(a1);
        rl[0][tid] = fmaxf(a0, 0.f);
        rl[1][tid] = fmaxf(a1, 0.f);
    }
    __syncthreads();
    if (tid < 14) {
        int b = tid / 7, i = tid % 7;
        float acc = fcb[i];
        const float* w = fcw + i * 300;
        for (int j = 0; j < 300; ++j) acc = fmaf(rl[b][j], w[j], acc);
        out[b*7 + i] = acc;
    }
}

// ---------------- host ----------------
extern "C" void kernel_launch(void* const* d_in, const int* in_sizes, int n_in,
                              void* d_out, int out_size, void* d_ws, size_t ws_size,
                              hipStream_t stream) {
    (void)in_sizes; (void)n_in; (void)out_size; (void)ws_size;
    const float* inp = (const float*)d_in[0];
    LayerParams lp;
    for (int l = 0; l < 6; ++l) {
        lp.tseq[l] = (const float*)d_in[1 + 3*l];
        lp.gw[l]   = (const float*)d_in[2 + 3*l];
        lp.gb[l]   = (const float*)d_in[3 + 3*l];
    }
    const float* fcw = (const float*)d_in[19];
    const float* fcb = (const float*)d_in[20];

    char* w = (char*)d_ws;
    float* sums = (float*)(w + OFF_SUMS);
    float* p0a = (float*)(w + OFF_P0A);
    float2* pza = (float2*)(w + OFF_PZA);
    float* p0b = (float*)(w + OFF_P0B);
    float2* pzb = (float2*)(w + OFF_PZB);
    float* dt = (float*)(w + OFF_DT);
    unsigned short* par = (unsigned short*)(w + OFF_PAR);
    u64* hp = (u64*)(w + OFF_HP);
    u64* hb = (u64*)(w + OFF_HB);
    u64* gmm = (u64*)(w + OFF_GMM);
    float* xbuf = (float*)(w + OFF_X);

    const int prefRows = 6*PW1v + 6*PW2v;
    hipLaunchKernelGGL(k_prefix, dim3(prefRows), dim3(64), 0, stream,
                       inp, p0a, pza, p0b, pzb);
    hipLaunchKernelGGL(k_sums2, dim3(6), dim3(256), 0, stream, p0a, sums);
    hipMemsetAsync(hp, 0xFF, (size_t)2*NFIELD*HSIZE*8 + 256, stream);
    const int maxslot = 3 * (BPF - DON64);   // 1920
    hipLaunchKernelGGL(k_dtm, dim3(8 * maxslot), dim3(64), 0, stream,
                       sums, p0a, pza, p0b, pzb, dt);
    hipLaunchKernelGGL(k_desc, dim3(NPIX/256, NFIELD), dim3(256), 0, stream, dt, par, gmm);
    hipLaunchKernelGGL(k_root, dim3(NFIELD), dim3(1024), 0, stream, par);
    hipLaunchKernelGGL(k_edges, dim3(NPIX/256, NFIELD), dim3(256), 0, stream, dt, par, hp, hb);
    hipLaunchKernelGGL(k_finish, dim3(NFIELD), dim3(1024), 0, stream, dt, gmm, hp, hb, lp, xbuf);
    hipLaunchKernelGGL(k_final, dim3(1), dim3(512), 0, stream, xbuf, fcw, fcb, (float*)d_out);
}